// Round 6
// baseline (171.515 us; speedup 1.0000x reference)
//
#include <hip/hip_runtime.h>
#include <math.h>

#define NB 32
#define NPTS 200000
#define N4 (NPTS / 4)
#define THREADS 256
#define BPB 64                    // blocks per batch -> grid 2048, 8 blocks/CU
#define IMG_W_C 1280.0f
#define IMG_H_C 384.0f

#define FINL __device__ __forceinline__

// Build M = K @ [R|t] (3x4, row-major). Called PER-THREAD so M lives in VGPRs.
// FORCEINLINE is load-bearing: R3/R5 showed that when the kernel grows (fused
// tail), the inliner stops inlining these helpers; the arrays then become
// scratch-homed and the kernel collapses to VGPR=32 / ~7x slower.
FINL void make_mat(const float* __restrict__ q4, const float* __restrict__ t3,
                   const float* __restrict__ K9, float* M) {
    float qw = q4[0], qx = q4[1], qy = q4[2], qz = q4[3];
    float inv = 1.0f / sqrtf(qw * qw + qx * qx + qy * qy + qz * qz);
    qw *= inv; qx *= inv; qy *= inv; qz *= inv;
    float R[9];
    R[0] = 1.f - 2.f * (qy * qy + qz * qz); R[1] = 2.f * (qx * qy - qz * qw); R[2] = 2.f * (qx * qz + qy * qw);
    R[3] = 2.f * (qx * qy + qz * qw); R[4] = 1.f - 2.f * (qx * qx + qz * qz); R[5] = 2.f * (qy * qz - qx * qw);
    R[6] = 2.f * (qx * qz - qy * qw); R[7] = 2.f * (qy * qz + qx * qw); R[8] = 1.f - 2.f * (qx * qx + qy * qy);
    #pragma unroll
    for (int i = 0; i < 3; i++) {
        float k0 = K9[i * 3 + 0], k1 = K9[i * 3 + 1], k2 = K9[i * 3 + 2];
        M[i * 4 + 0] = k0 * R[0] + k1 * R[3] + k2 * R[6];
        M[i * 4 + 1] = k0 * R[1] + k1 * R[4] + k2 * R[7];
        M[i * 4 + 2] = k0 * R[2] + k1 * R[5] + k2 * R[8];
        M[i * 4 + 3] = k0 * t3[0] + k1 * t3[1] + k2 * t3[2];
    }
}

FINL void point_contrib(const float* __restrict__ mg, const float* __restrict__ mp,
                        float cx, float cy, float x, float y, float z,
                        float& sw, float& se) {
    float g0 = fmaf(mg[0], x, fmaf(mg[1], y, fmaf(mg[2], z, mg[3])));
    float g1 = fmaf(mg[4], x, fmaf(mg[5], y, fmaf(mg[6], z, mg[7])));
    float g2 = fmaf(mg[8], x, fmaf(mg[9], y, fmaf(mg[10], z, mg[11])));
    float p0 = fmaf(mp[0], x, fmaf(mp[1], y, fmaf(mp[2], z, mp[3])));
    float p1 = fmaf(mp[4], x, fmaf(mp[5], y, fmaf(mp[6], z, mp[7])));
    float p2 = fmaf(mp[8], x, fmaf(mp[9], y, fmaf(mp[10], z, mp[11])));
    float ig = __builtin_amdgcn_rcpf(g2), ip = __builtin_amdgcn_rcpf(p2);
    float Fg = g0 * ig, Sg = g1 * ig;
    float F1 = p0 * ip, S1 = p1 * ip;

    // Exact collapse of the reference's 8-select chain:
    //   dF = (0<Fg<W && 0<F1<W) ? Fg-F1 : 0 (min-form), dS analog with H.
    float mF = fminf(fminf(Fg, F1), fminf(IMG_W_C - Fg, IMG_W_C - F1));
    float mS = fminf(fminf(Sg, S1), fminf(IMG_H_C - Sg, IMG_H_C - S1));
    float dF = (mF > 0.f) ? (Fg - F1) : 0.f;
    float dS = (mS > 0.f) ? (Sg - S1) : 0.f;

    float dx = Fg - cx, dy = Sg - cy;
    float rw = __builtin_amdgcn_rsqf(fmaf(dx, dx, dy * dy));   // raw w, always > 0
    sw += rw;
    se = fmaf(__builtin_amdgcn_sqrtf(fmaf(dF, dF, dS * dS)), rw, se);
}

// Runs ONCE, in the last block only. __noinline__ keeps the hot kernel body
// small so the inliner never flips on the helpers above.
__device__ __attribute__((noinline))
void finalize_tail(const float* __restrict__ tgt_t, const float* __restrict__ tgt_r,
                   const float* __restrict__ err_t, const float* __restrict__ err_r,
                   const float* __restrict__ partial, float* __restrict__ out) {
    const int bb = threadIdx.x;
    float val = 0.f;
    if (bb < NB) {
        float sw = 0.f, se = 0.f;
        for (int k = 0; k < BPB; k++) {
            sw += __hip_atomic_load(&partial[bb * BPB + k],
                                    __ATOMIC_ACQUIRE, __HIP_MEMORY_SCOPE_AGENT);
            se += __hip_atomic_load(&partial[NB * BPB + bb * BPB + k],
                                    __ATOMIC_ACQUIRE, __HIP_MEMORY_SCOPE_AGENT);
        }
        float pc_b = se / fmaxf(sw, 5.0f) * (1.0f / NPTS);

        // smooth-L1 translation loss
        float lt = 0.f;
        #pragma unroll
        for (int c = 0; c < 3; c++) {
            float d = err_t[bb * 3 + c] - tgt_t[bb * 3 + c];
            float ad = fabsf(d);
            lt += (ad < 1.0f) ? 0.5f * d * d : (ad - 0.5f);
        }

        // quaternion distance
        float qw = err_r[bb * 4], qx = err_r[bb * 4 + 1], qy = err_r[bb * 4 + 2], qz = err_r[bb * 4 + 3];
        float rn = 1.0f / sqrtf(qw * qw + qx * qx + qy * qy + qz * qz);
        qw *= rn; qx *= rn; qy *= rn; qz *= rn;
        float rw_ = tgt_r[bb * 4], rx = tgt_r[bb * 4 + 1], ry = tgt_r[bb * 4 + 2], rz = tgt_r[bb * 4 + 3];
        float rn2 = 1.0f / sqrtf(rw_ * rw_ + rx * rx + ry * ry + rz * rz);
        rw_ *= rn2; rx = -rx * rn2; ry = -ry * rn2; rz = -rz * rn2;  // r^-1
        float dw = qw * rw_ - qx * rx - qy * ry - qz * rz;
        float dx = qw * rx + qx * rw_ + qy * rz - qz * ry;
        float dy = qw * ry - qx * rz + qy * rw_ + qz * rx;
        float dz = qw * rz + qx * ry - qy * rx + qz * rw_;
        float lr = 2.0f * atan2f(sqrtf(dx * dx + dy * dy + dz * dz), fabsf(dw));

        val = 0.5f * (lr + lt) + 0.5f * pc_b;   // RESCALE=1, WEIGHT_PC=0.5
    }
    #pragma unroll
    for (int off = 32; off > 0; off >>= 1) val += __shfl_down(val, off);
    if (threadIdx.x == 0) out[0] = val * (1.0f / NB);
}

__global__ __launch_bounds__(THREADS)
void fused_loss(const float* __restrict__ pc,
                const float* __restrict__ tgt_t, const float* __restrict__ tgt_r,
                const float* __restrict__ err_t, const float* __restrict__ err_r,
                const float* __restrict__ cam,
                float* __restrict__ partial /* [2 * NB * BPB] */,
                unsigned int* __restrict__ ticket,
                float* __restrict__ out) {
    const int b  = blockIdx.x / BPB;
    const int cb = blockIdx.x % BPB;

    float mg[12], mp[12];
    make_mat(tgt_r + b * 4, tgt_t + b * 3, cam + b * 9, mg);
    make_mat(err_r + b * 4, err_t + b * 3, cam + b * 9, mp);
    const float cx = cam[b * 9 + 2];
    const float cy = cam[b * 9 + 5];

    // point_clouds (B, 4, N): planes x,y,z contiguous in n; plane 3 is all-ones (skipped).
    const float4* __restrict__ Xp = (const float4*)(pc + (size_t)b * 4 * NPTS);
    const float4* __restrict__ Yp = (const float4*)(pc + (size_t)b * 4 * NPTS + NPTS);
    const float4* __restrict__ Zp = (const float4*)(pc + (size_t)b * 4 * NPTS + 2 * NPTS);

    float sum_w = 0.f, sum_e = 0.f;
    constexpr int STRIDE = BPB * THREADS;
    for (int i = cb * THREADS + threadIdx.x; i < N4; i += STRIDE) {
        float4 xv = Xp[i], yv = Yp[i], zv = Zp[i];
        point_contrib(mg, mp, cx, cy, xv.x, yv.x, zv.x, sum_w, sum_e);
        point_contrib(mg, mp, cx, cy, xv.y, yv.y, zv.y, sum_w, sum_e);
        point_contrib(mg, mp, cx, cy, xv.z, yv.z, zv.z, sum_w, sum_e);
        point_contrib(mg, mp, cx, cy, xv.w, yv.w, zv.w, sum_w, sum_e);
    }

    // wave (64-lane) reduction, then cross-wave via LDS
    #pragma unroll
    for (int off = 32; off > 0; off >>= 1) {
        sum_w += __shfl_down(sum_w, off);
        sum_e += __shfl_down(sum_e, off);
    }
    __shared__ float red[2][THREADS / 64];
    const int wave = threadIdx.x >> 6, lane = threadIdx.x & 63;
    if (lane == 0) { red[0][wave] = sum_w; red[1][wave] = sum_e; }
    __syncthreads();

    __shared__ unsigned int sIsLast;
    if (threadIdx.x == 0) {
        float sw = 0.f, se = 0.f;
        #pragma unroll
        for (int k = 0; k < THREADS / 64; k++) { sw += red[0][k]; se += red[1][k]; }
        // Device-scope release stores: per-XCD L2s aren't cross-coherent.
        __hip_atomic_store(&partial[blockIdx.x], sw,
                           __ATOMIC_RELEASE, __HIP_MEMORY_SCOPE_AGENT);
        __hip_atomic_store(&partial[NB * BPB + blockIdx.x], se,
                           __ATOMIC_RELEASE, __HIP_MEMORY_SCOPE_AGENT);
        unsigned int old = __hip_atomic_fetch_add(ticket, 1u,
                           __ATOMIC_ACQ_REL, __HIP_MEMORY_SCOPE_AGENT);
        // Modulo ticket: exactly one block per call sees (old+1)%grid==0,
        // from ANY initial value (0xAA poison ok); 2048 | 2^32 so wrap is clean.
        sIsLast = ((old + 1u) % (unsigned int)gridDim.x == 0u) ? 1u : 0u;
    }
    __syncthreads();
    if (!sIsLast) return;

    finalize_tail(tgt_t, tgt_r, err_t, err_r, partial, out);
}

extern "C" void kernel_launch(void* const* d_in, const int* in_sizes, int n_in,
                              void* d_out, int out_size, void* d_ws, size_t ws_size,
                              hipStream_t stream) {
    const float* pc    = (const float*)d_in[0];
    const float* tgt_t = (const float*)d_in[1];
    const float* tgt_r = (const float*)d_in[2];
    const float* err_t = (const float*)d_in[3];
    const float* err_r = (const float*)d_in[4];
    const float* cam   = (const float*)d_in[5];
    float* out = (float*)d_out;

    unsigned int* ticket = (unsigned int*)d_ws;      // modulo scheme: no init needed
    float* partial = (float*)((char*)d_ws + 64);     // [2 * NB * BPB] floats

    fused_loss<<<NB * BPB, THREADS, 0, stream>>>(pc, tgt_t, tgt_r, err_t, err_r, cam,
                                                 partial, ticket, out);
}

// Round 8
// 29.696 us; speedup vs baseline: 5.7757x; 5.7757x over previous
//
#include <hip/hip_runtime.h>
#include <math.h>

#define NB 32
#define NPTS 200000
#define N4 (NPTS / 4)
#define THREADS 256
#define IMG_W_C 1280.0f
#define IMG_H_C 384.0f

#define FINL __device__ __forceinline__

// Build M = K @ [R|t] (3x4, row-major). Per-thread; block-uniform inputs let the
// compiler home M in SGPRs (R4: SGPR=64, VGPR=36 — matrices are scalar operands).
FINL void make_mat(const float* __restrict__ q4, const float* __restrict__ t3,
                   const float* __restrict__ K9, float* M) {
    float qw = q4[0], qx = q4[1], qy = q4[2], qz = q4[3];
    float inv = 1.0f / sqrtf(qw * qw + qx * qx + qy * qy + qz * qz);
    qw *= inv; qx *= inv; qy *= inv; qz *= inv;
    float R[9];
    R[0] = 1.f - 2.f * (qy * qy + qz * qz); R[1] = 2.f * (qx * qy - qz * qw); R[2] = 2.f * (qx * qz + qy * qw);
    R[3] = 2.f * (qx * qy + qz * qw); R[4] = 1.f - 2.f * (qx * qx + qz * qz); R[5] = 2.f * (qy * qz - qx * qw);
    R[6] = 2.f * (qx * qz - qy * qw); R[7] = 2.f * (qy * qz + qx * qw); R[8] = 1.f - 2.f * (qx * qx + qy * qy);
    #pragma unroll
    for (int i = 0; i < 3; i++) {
        float k0 = K9[i * 3 + 0], k1 = K9[i * 3 + 1], k2 = K9[i * 3 + 2];
        M[i * 4 + 0] = k0 * R[0] + k1 * R[3] + k2 * R[6];
        M[i * 4 + 1] = k0 * R[1] + k1 * R[4] + k2 * R[7];
        M[i * 4 + 2] = k0 * R[2] + k1 * R[5] + k2 * R[8];
        M[i * 4 + 3] = k0 * t3[0] + k1 * t3[1] + k2 * t3[2];
    }
}

FINL void point_contrib(const float* __restrict__ mg, const float* __restrict__ mp,
                        float cx, float cy, float x, float y, float z,
                        float& sw, float& se) {
    float g0 = fmaf(mg[0], x, fmaf(mg[1], y, fmaf(mg[2], z, mg[3])));
    float g1 = fmaf(mg[4], x, fmaf(mg[5], y, fmaf(mg[6], z, mg[7])));
    float g2 = fmaf(mg[8], x, fmaf(mg[9], y, fmaf(mg[10], z, mg[11])));
    float p0 = fmaf(mp[0], x, fmaf(mp[1], y, fmaf(mp[2], z, mp[3])));
    float p1 = fmaf(mp[4], x, fmaf(mp[5], y, fmaf(mp[6], z, mp[7])));
    float p2 = fmaf(mp[8], x, fmaf(mp[9], y, fmaf(mp[10], z, mp[11])));
    float ig = __builtin_amdgcn_rcpf(g2), ip = __builtin_amdgcn_rcpf(p2);
    float Fg = g0 * ig, Sg = g1 * ig;
    float F1 = p0 * ip, S1 = p1 * ip;

    // Exact collapse of the reference's 8-select chain:
    //   dF = (0<Fg<W && 0<F1<W) ? Fg-F1 : 0 (min-form), dS analog with H.
    float mF = fminf(fminf(Fg, F1), fminf(IMG_W_C - Fg, IMG_W_C - F1));
    float mS = fminf(fminf(Sg, S1), fminf(IMG_H_C - Sg, IMG_H_C - S1));
    float dF = (mF > 0.f) ? (Fg - F1) : 0.f;
    float dS = (mS > 0.f) ? (Sg - S1) : 0.f;

    float dx = Fg - cx, dy = Sg - cy;
    float rw = __builtin_amdgcn_rsqf(fmaf(dx, dx, dy * dy));   // raw w, always > 0
    sw += rw;
    se = fmaf(__builtin_amdgcn_sqrtf(fmaf(dF, dF, dS * dS)), rw, se);
}

FINL float pose_loss(int b, const float* __restrict__ tgt_t, const float* __restrict__ tgt_r,
                     const float* __restrict__ err_t, const float* __restrict__ err_r) {
    float lt = 0.f;
    #pragma unroll
    for (int c = 0; c < 3; c++) {
        float d = err_t[b * 3 + c] - tgt_t[b * 3 + c];
        float ad = fabsf(d);
        lt += (ad < 1.0f) ? 0.5f * d * d : (ad - 0.5f);
    }
    float qw = err_r[b * 4], qx = err_r[b * 4 + 1], qy = err_r[b * 4 + 2], qz = err_r[b * 4 + 3];
    float rn = 1.0f / sqrtf(qw * qw + qx * qx + qy * qy + qz * qz);
    qw *= rn; qx *= rn; qy *= rn; qz *= rn;
    float rw_ = tgt_r[b * 4], rx = tgt_r[b * 4 + 1], ry = tgt_r[b * 4 + 2], rz = tgt_r[b * 4 + 3];
    float rn2 = 1.0f / sqrtf(rw_ * rw_ + rx * rx + ry * ry + rz * rz);
    rw_ *= rn2; rx = -rx * rn2; ry = -ry * rn2; rz = -rz * rn2;  // r^-1
    float dw = qw * rw_ - qx * rx - qy * ry - qz * rz;
    float dx = qw * rx + qx * rw_ + qy * rz - qz * ry;
    float dy = qw * ry - qx * rz + qy * rw_ + qz * rx;
    float dz = qw * rz + qx * ry - qy * rx + qz * rw_;
    float lr = 2.0f * atan2f(sqrtf(dx * dx + dy * dy + dz * dz), fabsf(dw));
    return lr + lt;
}

#define P4(xv, yv, zv)                                                      \
    point_contrib(mg, mp, cx, cy, (xv).x, (yv).x, (zv).x, sum_w, sum_e);    \
    point_contrib(mg, mp, cx, cy, (xv).y, (yv).y, (zv).y, sum_w, sum_e);    \
    point_contrib(mg, mp, cx, cy, (xv).z, (yv).z, (zv).z, sum_w, sum_e);    \
    point_contrib(mg, mp, cx, cy, (xv).w, (yv).w, (zv).w, sum_w, sum_e);

// BPB=64: grid 2048. Each thread has exactly 3 guaranteed float4-iterations
// (i0+2*16384 <= 49151 < 50000) plus a 4th iff i0 < 912. Full unroll lets all
// 9 guaranteed loads issue back-to-back (one stall instead of three).
// __launch_bounds__(256,4): allow up to ~128 VGPRs so the load burst stays
// in registers (forcing 8 waves/EU would spill it to scratch).
template<int BPB>
__global__ __launch_bounds__(THREADS, 4)
void pc_partial(const float* __restrict__ pc,
                const float* __restrict__ tgt_t, const float* __restrict__ tgt_r,
                const float* __restrict__ err_t, const float* __restrict__ err_r,
                const float* __restrict__ cam,
                float* __restrict__ partial /* [2 * NB * BPB] */) {
    const int b  = blockIdx.x / BPB;
    const int cb = blockIdx.x % BPB;

    float mg[12], mp[12];
    make_mat(tgt_r + b * 4, tgt_t + b * 3, cam + b * 9, mg);
    make_mat(err_r + b * 4, err_t + b * 3, cam + b * 9, mp);
    const float cx = cam[b * 9 + 2];
    const float cy = cam[b * 9 + 5];

    // point_clouds (B, 4, N): planes x,y,z contiguous in n; ones-plane skipped.
    const float4* __restrict__ Xp = (const float4*)(pc + (size_t)b * 4 * NPTS);
    const float4* __restrict__ Yp = (const float4*)(pc + (size_t)b * 4 * NPTS + NPTS);
    const float4* __restrict__ Zp = (const float4*)(pc + (size_t)b * 4 * NPTS + 2 * NPTS);

    float sum_w = 0.f, sum_e = 0.f;
    constexpr int S = BPB * THREADS;
    const int i0 = cb * THREADS + threadIdx.x;

    if constexpr (S * 3 >= N4) {
        // Fully-unrolled path (BPB=64: S=16384, 3 guaranteed + 1 conditional).
        const int i1 = i0 + S, i2 = i0 + 2 * S, i3 = i0 + 3 * S;
        const bool m3 = (i3 < N4);
        float4 x0 = Xp[i0], y0 = Yp[i0], z0 = Zp[i0];
        float4 x1 = Xp[i1], y1 = Yp[i1], z1 = Zp[i1];
        float4 x2 = Xp[i2], y2 = Yp[i2], z2 = Zp[i2];
        float4 x3, y3, z3;
        if (m3) { x3 = Xp[i3]; y3 = Yp[i3]; z3 = Zp[i3]; }   // in flight during compute
        P4(x0, y0, z0)
        P4(x1, y1, z1)
        P4(x2, y2, z2)
        if (m3) { P4(x3, y3, z3) }
    } else {
        for (int i = i0; i < N4; i += S) {
            float4 xv = Xp[i], yv = Yp[i], zv = Zp[i];
            P4(xv, yv, zv)
        }
    }

    // wave (64-lane) reduction, then cross-wave via LDS
    #pragma unroll
    for (int off = 32; off > 0; off >>= 1) {
        sum_w += __shfl_down(sum_w, off);
        sum_e += __shfl_down(sum_e, off);
    }
    __shared__ float red[2][THREADS / 64];
    const int wave = threadIdx.x >> 6;
    if ((threadIdx.x & 63) == 0) { red[0][wave] = sum_w; red[1][wave] = sum_e; }
    __syncthreads();
    if (threadIdx.x == 0) {
        float sw = 0.f, se = 0.f;
        #pragma unroll
        for (int k = 0; k < THREADS / 64; k++) { sw += red[0][k]; se += red[1][k]; }
        partial[blockIdx.x] = sw;
        partial[NB * BPB + blockIdx.x] = se;
    }
}

__global__ __launch_bounds__(64)
void finalize(const float* __restrict__ tgt_t, const float* __restrict__ tgt_r,
              const float* __restrict__ err_t, const float* __restrict__ err_r,
              const float* __restrict__ partial, float* __restrict__ out, int bpb) {
    const int b = threadIdx.x;
    float val = 0.f;
    if (b < NB) {
        float sw = 0.f, se = 0.f;
        for (int i = 0; i < bpb; i++) {
            sw += partial[b * bpb + i];
            se += partial[NB * bpb + b * bpb + i];
        }
        float pc_b = se / fmaxf(sw, 5.0f) * (1.0f / NPTS);
        val = 0.5f * pose_loss(b, tgt_t, tgt_r, err_t, err_r) + 0.5f * pc_b;
    }
    #pragma unroll
    for (int off = 32; off > 0; off >>= 1) val += __shfl_down(val, off);
    if (threadIdx.x == 0) out[0] = val * (1.0f / NB);
}

extern "C" void kernel_launch(void* const* d_in, const int* in_sizes, int n_in,
                              void* d_out, int out_size, void* d_ws, size_t ws_size,
                              hipStream_t stream) {
    const float* pc    = (const float*)d_in[0];
    const float* tgt_t = (const float*)d_in[1];
    const float* tgt_r = (const float*)d_in[2];
    const float* err_t = (const float*)d_in[3];
    const float* err_r = (const float*)d_in[4];
    const float* cam   = (const float*)d_in[5];
    float* partial = (float*)d_ws;
    float* out = (float*)d_out;

    const int bpb = (ws_size >= (size_t)(2 * NB * 64 * sizeof(float))) ? 64 : 32;
    if (bpb == 64) {
        pc_partial<64><<<NB * 64, THREADS, 0, stream>>>(pc, tgt_t, tgt_r, err_t, err_r, cam, partial);
    } else {
        pc_partial<32><<<NB * 32, THREADS, 0, stream>>>(pc, tgt_t, tgt_r, err_t, err_r, cam, partial);
    }
    finalize<<<1, 64, 0, stream>>>(tgt_t, tgt_r, err_t, err_r, partial, out, bpb);
}

// Round 9
// 24.899 us; speedup vs baseline: 6.8885x; 1.1927x over previous
//
#include <hip/hip_runtime.h>
#include <math.h>

#define NB 32
#define NPTS 200000
#define N4 (NPTS / 4)
#define THREADS 256
#define IMG_W_C 1280.0f
#define IMG_H_C 384.0f

#define FINL __device__ __forceinline__

// Build M = K @ [R|t] (3x4, row-major). Per-thread; block-uniform inputs let the
// compiler home M in SGPRs (R4: SGPR=64, VGPR=36 — matrices are scalar operands).
FINL void make_mat(const float* __restrict__ q4, const float* __restrict__ t3,
                   const float* __restrict__ K9, float* M) {
    float qw = q4[0], qx = q4[1], qy = q4[2], qz = q4[3];
    float inv = 1.0f / sqrtf(qw * qw + qx * qx + qy * qy + qz * qz);
    qw *= inv; qx *= inv; qy *= inv; qz *= inv;
    float R[9];
    R[0] = 1.f - 2.f * (qy * qy + qz * qz); R[1] = 2.f * (qx * qy - qz * qw); R[2] = 2.f * (qx * qz + qy * qw);
    R[3] = 2.f * (qx * qy + qz * qw); R[4] = 1.f - 2.f * (qx * qx + qz * qz); R[5] = 2.f * (qy * qz - qx * qw);
    R[6] = 2.f * (qx * qz - qy * qw); R[7] = 2.f * (qy * qz + qx * qw); R[8] = 1.f - 2.f * (qx * qx + qy * qy);
    #pragma unroll
    for (int i = 0; i < 3; i++) {
        float k0 = K9[i * 3 + 0], k1 = K9[i * 3 + 1], k2 = K9[i * 3 + 2];
        M[i * 4 + 0] = k0 * R[0] + k1 * R[3] + k2 * R[6];
        M[i * 4 + 1] = k0 * R[1] + k1 * R[4] + k2 * R[7];
        M[i * 4 + 2] = k0 * R[2] + k1 * R[5] + k2 * R[8];
        M[i * 4 + 3] = k0 * t3[0] + k1 * t3[1] + k2 * t3[2];
    }
}

FINL void point_contrib(const float* __restrict__ mg, const float* __restrict__ mp,
                        float cx, float cy, float x, float y, float z,
                        float& sw, float& se) {
    float g0 = fmaf(mg[0], x, fmaf(mg[1], y, fmaf(mg[2], z, mg[3])));
    float g1 = fmaf(mg[4], x, fmaf(mg[5], y, fmaf(mg[6], z, mg[7])));
    float g2 = fmaf(mg[8], x, fmaf(mg[9], y, fmaf(mg[10], z, mg[11])));
    float p0 = fmaf(mp[0], x, fmaf(mp[1], y, fmaf(mp[2], z, mp[3])));
    float p1 = fmaf(mp[4], x, fmaf(mp[5], y, fmaf(mp[6], z, mp[7])));
    float p2 = fmaf(mp[8], x, fmaf(mp[9], y, fmaf(mp[10], z, mp[11])));
    float ig = __builtin_amdgcn_rcpf(g2), ip = __builtin_amdgcn_rcpf(p2);
    float Fg = g0 * ig, Sg = g1 * ig;
    float F1 = p0 * ip, S1 = p1 * ip;

    // Exact collapse of the reference's 8-select chain:
    //   dF = (0<Fg<W && 0<F1<W) ? Fg-F1 : 0 (min-form), dS analog with H.
    float mF = fminf(fminf(Fg, F1), fminf(IMG_W_C - Fg, IMG_W_C - F1));
    float mS = fminf(fminf(Sg, S1), fminf(IMG_H_C - Sg, IMG_H_C - S1));
    float dF = (mF > 0.f) ? (Fg - F1) : 0.f;
    float dS = (mS > 0.f) ? (Sg - S1) : 0.f;

    float dx = Fg - cx, dy = Sg - cy;
    float rw = __builtin_amdgcn_rsqf(fmaf(dx, dx, dy * dy));   // raw w, always > 0
    sw += rw;
    se = fmaf(__builtin_amdgcn_sqrtf(fmaf(dF, dF, dS * dS)), rw, se);
}

FINL float pose_loss(int b, const float* __restrict__ tgt_t, const float* __restrict__ tgt_r,
                     const float* __restrict__ err_t, const float* __restrict__ err_r) {
    float lt = 0.f;
    #pragma unroll
    for (int c = 0; c < 3; c++) {
        float d = err_t[b * 3 + c] - tgt_t[b * 3 + c];
        float ad = fabsf(d);
        lt += (ad < 1.0f) ? 0.5f * d * d : (ad - 0.5f);
    }
    float qw = err_r[b * 4], qx = err_r[b * 4 + 1], qy = err_r[b * 4 + 2], qz = err_r[b * 4 + 3];
    float rn = 1.0f / sqrtf(qw * qw + qx * qx + qy * qy + qz * qz);
    qw *= rn; qx *= rn; qy *= rn; qz *= rn;
    float rw_ = tgt_r[b * 4], rx = tgt_r[b * 4 + 1], ry = tgt_r[b * 4 + 2], rz = tgt_r[b * 4 + 3];
    float rn2 = 1.0f / sqrtf(rw_ * rw_ + rx * rx + ry * ry + rz * rz);
    rw_ *= rn2; rx = -rx * rn2; ry = -ry * rn2; rz = -rz * rn2;  // r^-1
    float dw = qw * rw_ - qx * rx - qy * ry - qz * rz;
    float dx = qw * rx + qx * rw_ + qy * rz - qz * ry;
    float dy = qw * ry - qx * rz + qy * rw_ + qz * rx;
    float dz = qw * rz + qx * ry - qy * rx + qz * rw_;
    float lr = 2.0f * atan2f(sqrtf(dx * dx + dy * dy + dz * dz), fabsf(dw));
    return lr + lt;
}

#define P4(xv, yv, zv)                                                      \
    point_contrib(mg, mp, cx, cy, (xv).x, (yv).x, (zv).x, sum_w, sum_e);    \
    point_contrib(mg, mp, cx, cy, (xv).y, (yv).y, (zv).y, sum_w, sum_e);    \
    point_contrib(mg, mp, cx, cy, (xv).z, (yv).z, (zv).z, sum_w, sum_e);    \
    point_contrib(mg, mp, cx, cy, (xv).w, (yv).w, (zv).w, sum_w, sum_e);

// Main kernel: identical to R8 (proven 29.7us floor for this phase), except the
// partial publish is now ONE coalesced float2 store (interleaved sw,se).
template<int BPB>
__global__ __launch_bounds__(THREADS, 4)
void pc_partial(const float* __restrict__ pc,
                const float* __restrict__ tgt_t, const float* __restrict__ tgt_r,
                const float* __restrict__ err_t, const float* __restrict__ err_r,
                const float* __restrict__ cam,
                float2* __restrict__ partial /* [NB * BPB] interleaved */) {
    const int b  = blockIdx.x / BPB;
    const int cb = blockIdx.x % BPB;

    float mg[12], mp[12];
    make_mat(tgt_r + b * 4, tgt_t + b * 3, cam + b * 9, mg);
    make_mat(err_r + b * 4, err_t + b * 3, cam + b * 9, mp);
    const float cx = cam[b * 9 + 2];
    const float cy = cam[b * 9 + 5];

    // point_clouds (B, 4, N): planes x,y,z contiguous in n; ones-plane skipped.
    const float4* __restrict__ Xp = (const float4*)(pc + (size_t)b * 4 * NPTS);
    const float4* __restrict__ Yp = (const float4*)(pc + (size_t)b * 4 * NPTS + NPTS);
    const float4* __restrict__ Zp = (const float4*)(pc + (size_t)b * 4 * NPTS + 2 * NPTS);

    float sum_w = 0.f, sum_e = 0.f;
    constexpr int S = BPB * THREADS;
    const int i0 = cb * THREADS + threadIdx.x;

    if constexpr (S * 3 >= N4) {
        const int i1 = i0 + S, i2 = i0 + 2 * S, i3 = i0 + 3 * S;
        const bool m3 = (i3 < N4);
        float4 x0 = Xp[i0], y0 = Yp[i0], z0 = Zp[i0];
        float4 x1 = Xp[i1], y1 = Yp[i1], z1 = Zp[i1];
        float4 x2 = Xp[i2], y2 = Yp[i2], z2 = Zp[i2];
        float4 x3, y3, z3;
        if (m3) { x3 = Xp[i3]; y3 = Yp[i3]; z3 = Zp[i3]; }
        P4(x0, y0, z0)
        P4(x1, y1, z1)
        P4(x2, y2, z2)
        if (m3) { P4(x3, y3, z3) }
    } else {
        for (int i = i0; i < N4; i += S) {
            float4 xv = Xp[i], yv = Yp[i], zv = Zp[i];
            P4(xv, yv, zv)
        }
    }

    #pragma unroll
    for (int off = 32; off > 0; off >>= 1) {
        sum_w += __shfl_down(sum_w, off);
        sum_e += __shfl_down(sum_e, off);
    }
    __shared__ float red[2][THREADS / 64];
    const int wave = threadIdx.x >> 6;
    if ((threadIdx.x & 63) == 0) { red[0][wave] = sum_w; red[1][wave] = sum_e; }
    __syncthreads();
    if (threadIdx.x == 0) {
        float sw = 0.f, se = 0.f;
        #pragma unroll
        for (int k = 0; k < THREADS / 64; k++) { sw += red[0][k]; se += red[1][k]; }
        partial[blockIdx.x] = make_float2(sw, se);
    }
}

// Parallel finalize: one block, 32 threads per batch, all partial loads
// coalesced float2. (Old version: 64 threads x 128 scattered scalar loads,
// a ~3-5us latency chain.)
template<int BPB>
__global__ __launch_bounds__(1024)
void finalize_par(const float* __restrict__ tgt_t, const float* __restrict__ tgt_r,
                  const float* __restrict__ err_t, const float* __restrict__ err_r,
                  const float2* __restrict__ partial, float* __restrict__ out) {
    const int tid = threadIdx.x;          // 0..1023
    const int b = tid >> 5;               // 32 threads per batch
    const int k = tid & 31;

    float sw = 0.f, se = 0.f;
    #pragma unroll
    for (int j = k; j < BPB; j += 32) {   // BPB=64: 2 coalesced float2 loads
        float2 p = partial[b * BPB + j];
        sw += p.x; se += p.y;
    }
    // reduce within the 32-lane group (32-aligned, xor stays in group)
    #pragma unroll
    for (int off = 16; off > 0; off >>= 1) {
        sw += __shfl_xor(sw, off);
        se += __shfl_xor(se, off);
    }

    __shared__ float sval[NB];
    if (k == 0) {
        float pc_b = se / fmaxf(sw, 5.0f) * (1.0f / NPTS);
        sval[b] = 0.5f * pose_loss(b, tgt_t, tgt_r, err_t, err_r) + 0.5f * pc_b;
    }
    __syncthreads();
    if (tid < 64) {
        float v = (tid < NB) ? sval[tid] : 0.f;
        #pragma unroll
        for (int off = 32; off > 0; off >>= 1) v += __shfl_down(v, off);
        if (tid == 0) out[0] = v * (1.0f / NB);
    }
}

extern "C" void kernel_launch(void* const* d_in, const int* in_sizes, int n_in,
                              void* d_out, int out_size, void* d_ws, size_t ws_size,
                              hipStream_t stream) {
    const float* pc    = (const float*)d_in[0];
    const float* tgt_t = (const float*)d_in[1];
    const float* tgt_r = (const float*)d_in[2];
    const float* err_t = (const float*)d_in[3];
    const float* err_r = (const float*)d_in[4];
    const float* cam   = (const float*)d_in[5];
    float2* partial = (float2*)d_ws;
    float* out = (float*)d_out;

    const int bpb = (ws_size >= (size_t)(NB * 64 * sizeof(float2))) ? 64 : 32;
    if (bpb == 64) {
        pc_partial<64><<<NB * 64, THREADS, 0, stream>>>(pc, tgt_t, tgt_r, err_t, err_r, cam, partial);
        finalize_par<64><<<1, 1024, 0, stream>>>(tgt_t, tgt_r, err_t, err_r, partial, out);
    } else {
        pc_partial<32><<<NB * 32, THREADS, 0, stream>>>(pc, tgt_t, tgt_r, err_t, err_r, cam, partial);
        finalize_par<32><<<1, 1024, 0, stream>>>(tgt_t, tgt_r, err_t, err_r, partial, out);
    }
}

// Round 10
// 24.068 us; speedup vs baseline: 7.1263x; 1.0345x over previous
//
#include <hip/hip_runtime.h>
#include <math.h>

#define NB 32
#define NPTS 200000
#define N4 (NPTS / 4)
#define THREADS 256
#define IMG_W_C 1280.0f
#define IMG_H_C 384.0f

#define FINL __device__ __forceinline__

// Build M = K @ [R|t] (3x4, row-major). Per-thread; block-uniform inputs let the
// compiler home M in SGPRs (matrices become scalar operands to v_fma).
FINL void make_mat(const float* __restrict__ q4, const float* __restrict__ t3,
                   const float* __restrict__ K9, float* M) {
    float qw = q4[0], qx = q4[1], qy = q4[2], qz = q4[3];
    float inv = 1.0f / sqrtf(qw * qw + qx * qx + qy * qy + qz * qz);
    qw *= inv; qx *= inv; qy *= inv; qz *= inv;
    float R[9];
    R[0] = 1.f - 2.f * (qy * qy + qz * qz); R[1] = 2.f * (qx * qy - qz * qw); R[2] = 2.f * (qx * qz + qy * qw);
    R[3] = 2.f * (qx * qy + qz * qw); R[4] = 1.f - 2.f * (qx * qx + qz * qz); R[5] = 2.f * (qy * qz - qx * qw);
    R[6] = 2.f * (qx * qz - qy * qw); R[7] = 2.f * (qy * qz + qx * qw); R[8] = 1.f - 2.f * (qx * qx + qy * qy);
    #pragma unroll
    for (int i = 0; i < 3; i++) {
        float k0 = K9[i * 3 + 0], k1 = K9[i * 3 + 1], k2 = K9[i * 3 + 2];
        M[i * 4 + 0] = k0 * R[0] + k1 * R[3] + k2 * R[6];
        M[i * 4 + 1] = k0 * R[1] + k1 * R[4] + k2 * R[7];
        M[i * 4 + 2] = k0 * R[2] + k1 * R[5] + k2 * R[8];
        M[i * 4 + 3] = k0 * t3[0] + k1 * t3[1] + k2 * t3[2];
    }
}

FINL void point_contrib(const float* __restrict__ mg, const float* __restrict__ mp,
                        float cx, float cy, float x, float y, float z,
                        float& sw, float& se) {
    float g0 = fmaf(mg[0], x, fmaf(mg[1], y, fmaf(mg[2], z, mg[3])));
    float g1 = fmaf(mg[4], x, fmaf(mg[5], y, fmaf(mg[6], z, mg[7])));
    float g2 = fmaf(mg[8], x, fmaf(mg[9], y, fmaf(mg[10], z, mg[11])));
    float p0 = fmaf(mp[0], x, fmaf(mp[1], y, fmaf(mp[2], z, mp[3])));
    float p1 = fmaf(mp[4], x, fmaf(mp[5], y, fmaf(mp[6], z, mp[7])));
    float p2 = fmaf(mp[8], x, fmaf(mp[9], y, fmaf(mp[10], z, mp[11])));
    float ig = __builtin_amdgcn_rcpf(g2), ip = __builtin_amdgcn_rcpf(p2);
    float Fg = g0 * ig, Sg = g1 * ig;
    float F1 = p0 * ip, S1 = p1 * ip;

    // Exact collapse of the reference's 8-select chain:
    //   dF = (0<Fg<W && 0<F1<W) ? Fg-F1 : 0 (min-form), dS analog with H.
    float mF = fminf(fminf(Fg, F1), fminf(IMG_W_C - Fg, IMG_W_C - F1));
    float mS = fminf(fminf(Sg, S1), fminf(IMG_H_C - Sg, IMG_H_C - S1));
    float dF = (mF > 0.f) ? (Fg - F1) : 0.f;
    float dS = (mS > 0.f) ? (Sg - S1) : 0.f;

    float dx = Fg - cx, dy = Sg - cy;
    float rw = __builtin_amdgcn_rsqf(fmaf(dx, dx, dy * dy));   // raw w, always > 0
    sw += rw;
    se = fmaf(__builtin_amdgcn_sqrtf(fmaf(dF, dF, dS * dS)), rw, se);
}

FINL float pose_loss(int b, const float* __restrict__ tgt_t, const float* __restrict__ tgt_r,
                     const float* __restrict__ err_t, const float* __restrict__ err_r) {
    float lt = 0.f;
    #pragma unroll
    for (int c = 0; c < 3; c++) {
        float d = err_t[b * 3 + c] - tgt_t[b * 3 + c];
        float ad = fabsf(d);
        lt += (ad < 1.0f) ? 0.5f * d * d : (ad - 0.5f);
    }
    float qw = err_r[b * 4], qx = err_r[b * 4 + 1], qy = err_r[b * 4 + 2], qz = err_r[b * 4 + 3];
    float rn = 1.0f / sqrtf(qw * qw + qx * qx + qy * qy + qz * qz);
    qw *= rn; qx *= rn; qy *= rn; qz *= rn;
    float rw_ = tgt_r[b * 4], rx = tgt_r[b * 4 + 1], ry = tgt_r[b * 4 + 2], rz = tgt_r[b * 4 + 3];
    float rn2 = 1.0f / sqrtf(rw_ * rw_ + rx * rx + ry * ry + rz * rz);
    rw_ *= rn2; rx = -rx * rn2; ry = -ry * rn2; rz = -rz * rn2;  // r^-1
    float dw = qw * rw_ - qx * rx - qy * ry - qz * rz;
    float dx = qw * rx + qx * rw_ + qy * rz - qz * ry;
    float dy = qw * ry - qx * rz + qy * rw_ + qz * rx;
    float dz = qw * rz + qx * ry - qy * rx + qz * rw_;
    float lr = 2.0f * atan2f(sqrtf(dx * dx + dy * dy + dz * dz), fabsf(dw));
    return lr + lt;
}

#define P4(xv, yv, zv)                                                      \
    point_contrib(mg, mp, cx, cy, (xv).x, (yv).x, (zv).x, sum_w, sum_e);    \
    point_contrib(mg, mp, cx, cy, (xv).y, (yv).y, (zv).y, sum_w, sum_e);    \
    point_contrib(mg, mp, cx, cy, (xv).z, (yv).z, (zv).z, sum_w, sum_e);    \
    point_contrib(mg, mp, cx, cy, (xv).w, (yv).w, (zv).w, sum_w, sum_e);

// Balanced block-chunked partition: block cb owns float4s [cb*CHUNK, cb*CHUNK+CHUNK)
// (clamped). CHUNK=782 for BPB=64 -> every block runs 3 full iters + a 14-thread
// partial; no 4-iteration straggler blocks (R9's grid-stride left 128 of 2048
// blocks doing 33% extra work, defining the kernel's drained-machine tail).
// Lane i reads base+tid+k*256 -> fully coalesced.
template<int BPB>
__global__ __launch_bounds__(THREADS, 4)
void pc_partial(const float* __restrict__ pc,
                const float* __restrict__ tgt_t, const float* __restrict__ tgt_r,
                const float* __restrict__ err_t, const float* __restrict__ err_r,
                const float* __restrict__ cam,
                float2* __restrict__ partial /* [NB * BPB] interleaved */) {
    const int b  = blockIdx.x / BPB;
    const int cb = blockIdx.x % BPB;

    float mg[12], mp[12];
    make_mat(tgt_r + b * 4, tgt_t + b * 3, cam + b * 9, mg);
    make_mat(err_r + b * 4, err_t + b * 3, cam + b * 9, mp);
    const float cx = cam[b * 9 + 2];
    const float cy = cam[b * 9 + 5];

    // point_clouds (B, 4, N): planes x,y,z contiguous in n; ones-plane skipped.
    const float4* __restrict__ Xp = (const float4*)(pc + (size_t)b * 4 * NPTS);
    const float4* __restrict__ Yp = (const float4*)(pc + (size_t)b * 4 * NPTS + NPTS);
    const float4* __restrict__ Zp = (const float4*)(pc + (size_t)b * 4 * NPTS + 2 * NPTS);

    float sum_w = 0.f, sum_e = 0.f;
    constexpr int CHUNK = (N4 + BPB - 1) / BPB;
    const int base = cb * CHUNK;
    const int lim  = (base + CHUNK < N4) ? (base + CHUNK) : N4;

    for (int i = base + (int)threadIdx.x; i < lim; i += THREADS) {
        float4 xv = Xp[i], yv = Yp[i], zv = Zp[i];
        P4(xv, yv, zv)
    }

    #pragma unroll
    for (int off = 32; off > 0; off >>= 1) {
        sum_w += __shfl_down(sum_w, off);
        sum_e += __shfl_down(sum_e, off);
    }
    __shared__ float red[2][THREADS / 64];
    const int wave = threadIdx.x >> 6;
    if ((threadIdx.x & 63) == 0) { red[0][wave] = sum_w; red[1][wave] = sum_e; }
    __syncthreads();
    if (threadIdx.x == 0) {
        float sw = 0.f, se = 0.f;
        #pragma unroll
        for (int k = 0; k < THREADS / 64; k++) { sw += red[0][k]; se += red[1][k]; }
        partial[blockIdx.x] = make_float2(sw, se);
    }
}

// Parallel finalize (R9, matched prediction: ~1.5us): one block, 32 threads per
// batch, all partial loads coalesced float2.
template<int BPB>
__global__ __launch_bounds__(1024)
void finalize_par(const float* __restrict__ tgt_t, const float* __restrict__ tgt_r,
                  const float* __restrict__ err_t, const float* __restrict__ err_r,
                  const float2* __restrict__ partial, float* __restrict__ out) {
    const int tid = threadIdx.x;          // 0..1023
    const int b = tid >> 5;               // 32 threads per batch
    const int k = tid & 31;

    float sw = 0.f, se = 0.f;
    #pragma unroll
    for (int j = k; j < BPB; j += 32) {   // BPB=64: 2 coalesced float2 loads
        float2 p = partial[b * BPB + j];
        sw += p.x; se += p.y;
    }
    #pragma unroll
    for (int off = 16; off > 0; off >>= 1) {
        sw += __shfl_xor(sw, off);
        se += __shfl_xor(se, off);
    }

    __shared__ float sval[NB];
    if (k == 0) {
        float pc_b = se / fmaxf(sw, 5.0f) * (1.0f / NPTS);
        sval[b] = 0.5f * pose_loss(b, tgt_t, tgt_r, err_t, err_r) + 0.5f * pc_b;
    }
    __syncthreads();
    if (tid < 64) {
        float v = (tid < NB) ? sval[tid] : 0.f;
        #pragma unroll
        for (int off = 32; off > 0; off >>= 1) v += __shfl_down(v, off);
        if (tid == 0) out[0] = v * (1.0f / NB);
    }
}

extern "C" void kernel_launch(void* const* d_in, const int* in_sizes, int n_in,
                              void* d_out, int out_size, void* d_ws, size_t ws_size,
                              hipStream_t stream) {
    const float* pc    = (const float*)d_in[0];
    const float* tgt_t = (const float*)d_in[1];
    const float* tgt_r = (const float*)d_in[2];
    const float* err_t = (const float*)d_in[3];
    const float* err_r = (const float*)d_in[4];
    const float* cam   = (const float*)d_in[5];
    float2* partial = (float2*)d_ws;
    float* out = (float*)d_out;

    const int bpb = (ws_size >= (size_t)(NB * 64 * sizeof(float2))) ? 64 : 32;
    if (bpb == 64) {
        pc_partial<64><<<NB * 64, THREADS, 0, stream>>>(pc, tgt_t, tgt_r, err_t, err_r, cam, partial);
        finalize_par<64><<<1, 1024, 0, stream>>>(tgt_t, tgt_r, err_t, err_r, partial, out);
    } else {
        pc_partial<32><<<NB * 32, THREADS, 0, stream>>>(pc, tgt_t, tgt_r, err_t, err_r, cam, partial);
        finalize_par<32><<<1, 1024, 0, stream>>>(tgt_t, tgt_r, err_t, err_r, partial, out);
    }
}

// Round 11
// 23.767 us; speedup vs baseline: 7.2164x; 1.0126x over previous
//
#include <hip/hip_runtime.h>
#include <math.h>

#define NB 32
#define NPTS 200000
#define N4 (NPTS / 4)
#define THREADS 512               // R11: 512-thread blocks halve per-block fixed costs
#define BPB 32                    // grid = NB*BPB = 1024 blocks; CHUNK = 1563
#define IMG_W_C 1280.0f
#define IMG_H_C 384.0f

#define FINL __device__ __forceinline__

// Build M = K @ [R|t] (3x4, row-major). Per-thread; block-uniform inputs let the
// compiler home M in SGPRs (matrices become scalar operands to v_fma).
FINL void make_mat(const float* __restrict__ q4, const float* __restrict__ t3,
                   const float* __restrict__ K9, float* M) {
    float qw = q4[0], qx = q4[1], qy = q4[2], qz = q4[3];
    float inv = __builtin_amdgcn_rsqf(qw * qw + qx * qx + qy * qy + qz * qz);  // 1-ulp, per-thread cost matters
    qw *= inv; qx *= inv; qy *= inv; qz *= inv;
    float R[9];
    R[0] = 1.f - 2.f * (qy * qy + qz * qz); R[1] = 2.f * (qx * qy - qz * qw); R[2] = 2.f * (qx * qz + qy * qw);
    R[3] = 2.f * (qx * qy + qz * qw); R[4] = 1.f - 2.f * (qx * qx + qz * qz); R[5] = 2.f * (qy * qz - qx * qw);
    R[6] = 2.f * (qx * qz - qy * qw); R[7] = 2.f * (qy * qz + qx * qw); R[8] = 1.f - 2.f * (qx * qx + qy * qy);
    #pragma unroll
    for (int i = 0; i < 3; i++) {
        float k0 = K9[i * 3 + 0], k1 = K9[i * 3 + 1], k2 = K9[i * 3 + 2];
        M[i * 4 + 0] = k0 * R[0] + k1 * R[3] + k2 * R[6];
        M[i * 4 + 1] = k0 * R[1] + k1 * R[4] + k2 * R[7];
        M[i * 4 + 2] = k0 * R[2] + k1 * R[5] + k2 * R[8];
        M[i * 4 + 3] = k0 * t3[0] + k1 * t3[1] + k2 * t3[2];
    }
}

FINL void point_contrib(const float* __restrict__ mg, const float* __restrict__ mp,
                        float cx, float cy, float x, float y, float z,
                        float& sw, float& se) {
    float g0 = fmaf(mg[0], x, fmaf(mg[1], y, fmaf(mg[2], z, mg[3])));
    float g1 = fmaf(mg[4], x, fmaf(mg[5], y, fmaf(mg[6], z, mg[7])));
    float g2 = fmaf(mg[8], x, fmaf(mg[9], y, fmaf(mg[10], z, mg[11])));
    float p0 = fmaf(mp[0], x, fmaf(mp[1], y, fmaf(mp[2], z, mp[3])));
    float p1 = fmaf(mp[4], x, fmaf(mp[5], y, fmaf(mp[6], z, mp[7])));
    float p2 = fmaf(mp[8], x, fmaf(mp[9], y, fmaf(mp[10], z, mp[11])));
    float ig = __builtin_amdgcn_rcpf(g2), ip = __builtin_amdgcn_rcpf(p2);
    float Fg = g0 * ig, Sg = g1 * ig;
    float F1 = p0 * ip, S1 = p1 * ip;

    // Exact collapse of the reference's 8-select chain:
    //   dF = (0<Fg<W && 0<F1<W) ? Fg-F1 : 0 (min-form), dS analog with H.
    float mF = fminf(fminf(Fg, F1), fminf(IMG_W_C - Fg, IMG_W_C - F1));
    float mS = fminf(fminf(Sg, S1), fminf(IMG_H_C - Sg, IMG_H_C - S1));
    float dF = (mF > 0.f) ? (Fg - F1) : 0.f;
    float dS = (mS > 0.f) ? (Sg - S1) : 0.f;

    float dx = Fg - cx, dy = Sg - cy;
    float rw = __builtin_amdgcn_rsqf(fmaf(dx, dx, dy * dy));   // raw w, always > 0
    sw += rw;
    se = fmaf(__builtin_amdgcn_sqrtf(fmaf(dF, dF, dS * dS)), rw, se);
}

FINL float pose_loss(int b, const float* __restrict__ tgt_t, const float* __restrict__ tgt_r,
                     const float* __restrict__ err_t, const float* __restrict__ err_r) {
    float lt = 0.f;
    #pragma unroll
    for (int c = 0; c < 3; c++) {
        float d = err_t[b * 3 + c] - tgt_t[b * 3 + c];
        float ad = fabsf(d);
        lt += (ad < 1.0f) ? 0.5f * d * d : (ad - 0.5f);
    }
    float qw = err_r[b * 4], qx = err_r[b * 4 + 1], qy = err_r[b * 4 + 2], qz = err_r[b * 4 + 3];
    float rn = 1.0f / sqrtf(qw * qw + qx * qx + qy * qy + qz * qz);
    qw *= rn; qx *= rn; qy *= rn; qz *= rn;
    float rw_ = tgt_r[b * 4], rx = tgt_r[b * 4 + 1], ry = tgt_r[b * 4 + 2], rz = tgt_r[b * 4 + 3];
    float rn2 = 1.0f / sqrtf(rw_ * rw_ + rx * rx + ry * ry + rz * rz);
    rw_ *= rn2; rx = -rx * rn2; ry = -ry * rn2; rz = -rz * rn2;  // r^-1
    float dw = qw * rw_ - qx * rx - qy * ry - qz * rz;
    float dx = qw * rx + qx * rw_ + qy * rz - qz * ry;
    float dy = qw * ry - qx * rz + qy * rw_ + qz * rx;
    float dz = qw * rz + qx * ry - qy * rx + qz * rw_;
    float lr = 2.0f * atan2f(sqrtf(dx * dx + dy * dy + dz * dz), fabsf(dw));
    return lr + lt;
}

#define P4(xv, yv, zv)                                                      \
    point_contrib(mg, mp, cx, cy, (xv).x, (yv).x, (zv).x, sum_w, sum_e);    \
    point_contrib(mg, mp, cx, cy, (xv).y, (yv).y, (zv).y, sum_w, sum_e);    \
    point_contrib(mg, mp, cx, cy, (xv).z, (yv).z, (zv).z, sum_w, sum_e);    \
    point_contrib(mg, mp, cx, cy, (xv).w, (yv).w, (zv).w, sum_w, sum_e);

// Balanced block-chunked partition (R10): block cb owns float4s
// [cb*CHUNK, min(cb*CHUNK+CHUNK, N4)). CHUNK=1563 @ THREADS=512 -> every block
// runs 3 full iterations + a 27-thread partial; coalesced (lane i at base+tid).
__global__ __launch_bounds__(THREADS, 4)
void pc_partial(const float* __restrict__ pc,
                const float* __restrict__ tgt_t, const float* __restrict__ tgt_r,
                const float* __restrict__ err_t, const float* __restrict__ err_r,
                const float* __restrict__ cam,
                float2* __restrict__ partial /* [NB * BPB] interleaved */) {
    const int b  = blockIdx.x / BPB;
    const int cb = blockIdx.x % BPB;

    float mg[12], mp[12];
    make_mat(tgt_r + b * 4, tgt_t + b * 3, cam + b * 9, mg);
    make_mat(err_r + b * 4, err_t + b * 3, cam + b * 9, mp);
    const float cx = cam[b * 9 + 2];
    const float cy = cam[b * 9 + 5];

    // point_clouds (B, 4, N): planes x,y,z contiguous in n; ones-plane skipped.
    const float4* __restrict__ Xp = (const float4*)(pc + (size_t)b * 4 * NPTS);
    const float4* __restrict__ Yp = (const float4*)(pc + (size_t)b * 4 * NPTS + NPTS);
    const float4* __restrict__ Zp = (const float4*)(pc + (size_t)b * 4 * NPTS + 2 * NPTS);

    float sum_w = 0.f, sum_e = 0.f;
    constexpr int CHUNK = (N4 + BPB - 1) / BPB;
    const int base = cb * CHUNK;
    const int lim  = (base + CHUNK < N4) ? (base + CHUNK) : N4;

    for (int i = base + (int)threadIdx.x; i < lim; i += THREADS) {
        float4 xv = Xp[i], yv = Yp[i], zv = Zp[i];
        P4(xv, yv, zv)
    }

    #pragma unroll
    for (int off = 32; off > 0; off >>= 1) {
        sum_w += __shfl_down(sum_w, off);
        sum_e += __shfl_down(sum_e, off);
    }
    __shared__ float red[2][THREADS / 64];
    const int wave = threadIdx.x >> 6;
    if ((threadIdx.x & 63) == 0) { red[0][wave] = sum_w; red[1][wave] = sum_e; }
    __syncthreads();
    if (threadIdx.x == 0) {
        float sw = 0.f, se = 0.f;
        #pragma unroll
        for (int k = 0; k < THREADS / 64; k++) { sw += red[0][k]; se += red[1][k]; }
        partial[blockIdx.x] = make_float2(sw, se);
    }
}

// Parallel finalize (R9, verified ~1.5us): one block, 32 threads per batch,
// coalesced float2 loads of the partials.
__global__ __launch_bounds__(1024)
void finalize_par(const float* __restrict__ tgt_t, const float* __restrict__ tgt_r,
                  const float* __restrict__ err_t, const float* __restrict__ err_r,
                  const float2* __restrict__ partial, float* __restrict__ out) {
    const int tid = threadIdx.x;          // 0..1023
    const int b = tid >> 5;               // 32 threads per batch
    const int k = tid & 31;

    float sw = 0.f, se = 0.f;
    #pragma unroll
    for (int j = k; j < BPB; j += 32) {   // BPB=32: 1 coalesced float2 load
        float2 p = partial[b * BPB + j];
        sw += p.x; se += p.y;
    }
    #pragma unroll
    for (int off = 16; off > 0; off >>= 1) {
        sw += __shfl_xor(sw, off);
        se += __shfl_xor(se, off);
    }

    __shared__ float sval[NB];
    if (k == 0) {
        float pc_b = se / fmaxf(sw, 5.0f) * (1.0f / NPTS);
        sval[b] = 0.5f * pose_loss(b, tgt_t, tgt_r, err_t, err_r) + 0.5f * pc_b;
    }
    __syncthreads();
    if (tid < 64) {
        float v = (tid < NB) ? sval[tid] : 0.f;
        #pragma unroll
        for (int off = 32; off > 0; off >>= 1) v += __shfl_down(v, off);
        if (tid == 0) out[0] = v * (1.0f / NB);
    }
}

extern "C" void kernel_launch(void* const* d_in, const int* in_sizes, int n_in,
                              void* d_out, int out_size, void* d_ws, size_t ws_size,
                              hipStream_t stream) {
    const float* pc    = (const float*)d_in[0];
    const float* tgt_t = (const float*)d_in[1];
    const float* tgt_r = (const float*)d_in[2];
    const float* err_t = (const float*)d_in[3];
    const float* err_r = (const float*)d_in[4];
    const float* cam   = (const float*)d_in[5];
    float2* partial = (float2*)d_ws;      // NB*BPB float2 = 8 KB
    float* out = (float*)d_out;

    pc_partial<<<NB * BPB, THREADS, 0, stream>>>(pc, tgt_t, tgt_r, err_t, err_r, cam, partial);
    finalize_par<<<1, 1024, 0, stream>>>(tgt_t, tgt_r, err_t, err_r, partial, out);
}